// Round 8
// baseline (24.794 us; speedup 1.0000x reference)
//
#include <hip/hip_runtime.h>
#include <cstdint>

// ---------------- problem constants ----------------
static constexpr int RPI    = 256;   // ROIS_PER_IMAGE
static constexpr int MAXPOS = 64;    // round(256*0.25)
static constexpr int MAX_GT = 256;   // LDS capacity for gt boxes (M=200)
static constexpr int MAXG   = 4096;  // max 64-ROI groups (N <= 262144)
static constexpr int NBLK_A = 32;    // phase-A blocks (128 ROIs each -> 64 groups)

// ---------------- workspace layout (bytes) ----------------
static constexpr size_t WS_CNT    = 0;                                  // int: slow-path arrivals
static constexpr size_t WS_GRPPK  = 64;                                 // packed (pos<<16|neg)
static constexpr size_t WS_BESTGT = WS_GRPPK + (size_t)MAXG * 4;        // int16 per ROI
static constexpr size_t WS_KEY    = WS_BESTGT + (size_t)262144 * 2;     // uint8 per ROI

// ---------------- shared IoU block body (R3/R6/R7-proven, absmax 0) --------------
// Block = 256 thr = 4 waves, owns 128 ROIs (2/lane); each wave handles ITS
// quarter of the GT list; partials merged in segment order. Rational argmax
// tracking (bi,c1): r_c > r_b <=> I_c*c1_b > bi_b*S_c. Winner's IoU
// RECOMPUTED in exact reference op order, ONE IEEE divide -> bit-exact.
struct IouSmem {
    float4 sgt[MAX_GT];
    float  sarea[MAX_GT];
    float  sabe[MAX_GT];
    float  sbi[4][128];
    float  sc1[4][128];
    short  sbj[4][128];
};

__device__ __forceinline__ void iou_block(
    IouSmem& S, const float* __restrict__ rois, const float* __restrict__ gts,
    int N, int M, int blk,
    uint8_t* __restrict__ key, int16_t* __restrict__ bestgt,
    int* __restrict__ grpPk)
{
#pragma clang fp contract(off)
    const int tid = threadIdx.x;
    for (int j = tid; j < M; j += 256) {
        float4 g = ((const float4*)gts)[j];
        S.sgt[j] = g;
        float a = (g.z - g.x) * (g.w - g.y);   // ref op order
        S.sarea[j] = a;
        S.sabe[j]  = a + 1e-7f;
    }
    __syncthreads();

    const int w = tid >> 6, l = tid & 63;
    const int base = blk * 128;
    const int r0 = base + l, r1 = r0 + 64;
    const float4 zb = make_float4(0.f, 0.f, 0.f, 0.f);
    float4 b0 = (r0 < N) ? ((const float4*)rois)[r0] : zb;
    float4 b1 = (r1 < N) ? ((const float4*)rois)[r1] : zb;
    float aA0 = (b0.z - b0.x) * (b0.w - b0.y);
    float aA1 = (b1.z - b1.x) * (b1.w - b1.y);

    const int seglen = (M + 3) >> 2;
    const int j0 = w * seglen, j1 = min(M, j0 + seglen);

    float bi0 = -1.f, c10 = 0.f, bi1 = -1.f, c11 = 0.f;   // first j always wins
    int   bj0 = j0,   bj1 = j0;

    float4 g  = S.sgt[j0];               // sized-256 arrays: j+1 read in-bounds
    float  ae = S.sabe[j0];
#pragma unroll 2
    for (int j = j0; j < j1; ++j) {
        float4 gn = S.sgt[j + 1];        // register prefetch
        float  an = S.sabe[j + 1];
        {
            float ih = fmaxf(fminf(b0.z, g.z) - fmaxf(b0.x, g.x), 0.f);
            float iw = fmaxf(fminf(b0.w, g.w) - fmaxf(b0.y, g.y), 0.f);
            float inter = ih * iw;
            float Sx = aA0 + ae;
            bool  s = (inter * c10) > (bi0 * Sx);
            bi0 = s ? inter : bi0;  c10 = s ? Sx : c10;  bj0 = s ? j : bj0;
        }
        {
            float ih = fmaxf(fminf(b1.z, g.z) - fmaxf(b1.x, g.x), 0.f);
            float iw = fmaxf(fminf(b1.w, g.w) - fmaxf(b1.y, g.y), 0.f);
            float inter = ih * iw;
            float Sx = aA1 + ae;
            bool  s = (inter * c11) > (bi1 * Sx);
            bi1 = s ? inter : bi1;  c11 = s ? Sx : c11;  bj1 = s ? j : bj1;
        }
        g = gn; ae = an;
    }
    S.sbi[w][l]      = bi0;  S.sc1[w][l]      = c10;  S.sbj[w][l]      = (short)bj0;
    S.sbi[w][64 + l] = bi1;  S.sc1[w][64 + l] = c11;  S.sbj[w][64 + l] = (short)bj1;
    __syncthreads();

    if (tid < 128) {
        float BI = S.sbi[0][tid], C1 = S.sc1[0][tid];
        int   BJ = (int)S.sbj[0][tid];
#pragma unroll
        for (int s2 = 1; s2 < 4; ++s2) {
            float ci = S.sbi[s2][tid], cc = S.sc1[s2][tid];
            bool sel = (ci * C1) > (BI * cc);
            BI = sel ? ci : BI;  C1 = sel ? cc : C1;
            BJ = sel ? (int)S.sbj[s2][tid] : BJ;
        }
        float4 bb = (tid < 64) ? b0 : b1;   // thread tid holds box of ROI base+tid
        float  aa = (tid < 64) ? aA0 : aA1;
        int r = base + tid;
        int kk = 2;
        if (r < N) {
            float4 gg = S.sgt[BJ];
            float  ab = S.sarea[BJ];
            float ih = fmaxf(fminf(bb.z, gg.z) - fmaxf(bb.x, gg.x), 0.f);
            float iw = fmaxf(fminf(bb.w, gg.w) - fmaxf(bb.y, gg.y), 0.f);
            float inter = ih * iw;
            float u1 = ((aa + ab) - inter) + 1e-7f;   // exact ref op order
            float q  = inter / u1;                    // the ONLY division
            kk = (q > 0.5f) ? 0 : ((q < 0.5f && q > 0.1f) ? 1 : 2);
            key[r]    = (uint8_t)kk;
            bestgt[r] = (int16_t)BJ;
        }
        unsigned long long mp = __ballot(kk == 0);
        unsigned long long mn = __ballot(kk == 1);
        if (l == 0)
            grpPk[blk * 2 + w] = (__popcll(mp) << 16) | __popcll(mn);
    }
}

// ---------------- kernel 1: phase A — exact IoU on the first 4096 ROIs -----------
__global__ __launch_bounds__(256) void iouA_kernel(
    const float* __restrict__ rois, const float* __restrict__ gts,
    int N, int M,
    uint8_t* __restrict__ key, int16_t* __restrict__ bestgt,
    int* __restrict__ grpPk, int* __restrict__ cnt)
{
    __shared__ IouSmem S;
    if (blockIdx.x == 0 && threadIdx.x == 0) cnt[0] = 0;  // arm slow-path counter
    iou_block(S, rois, gts, N, M, (int)blockIdx.x, key, bestgt, grpPk);
}

// ---------------- kernel 2: megakernel — quota-gated phase C + finish ------------
// Every block inlines the quota check over the phase-A prefix. If the prefix
// holds >= MAXPOS positives and >= RPI-MAXPOS negatives, tp/tn saturate
// exactly and all selected ROIs are in the prefix -> C blocks exit, finish
// block needs NO sibling data (fast path: zero cross-block dependencies).
// Slow path (never taken on this input): C blocks compute + release-fence +
// arrival atomic; finish block spins, then does the full totals reduction.
__global__ __launch_bounds__(256) void mega_kernel(
    const float* __restrict__ rois, const float* __restrict__ gts,
    const int* __restrict__ labels,
    int N, int M,
    uint8_t* __restrict__ key, int16_t* __restrict__ bestgt,
    int* __restrict__ grpPk, int* __restrict__ cnt,
    float* __restrict__ outD, float* __restrict__ outH,
    int kgrp, int nblkC, int ngroups)
{
#pragma clang fp contract(off)
    __shared__ IouSmem S;
    __shared__ int slot[RPI], slab[RPI];
    __shared__ int redP[4], redN[4];
    __shared__ int s_fast, s_tp, s_tn;

    const int tid = threadIdx.x, w = tid >> 6, l = tid & 63;

    // ---- inline quota check (all blocks; wave 0 computes, LDS broadcast) ----
    if (w == 0) {
        int v = (l < kgrp) ? grpPk[l] : 0;
        int p = v >> 16, n = v & 0xFFFF;
#pragma unroll
        for (int o = 1; o < 64; o <<= 1) {
            p += __shfl_xor(p, o);
            n += __shfl_xor(n, o);
        }
        if (l == 0) s_fast = (p >= MAXPOS && n >= RPI - MAXPOS) ? 1 : 0;
    }
    __syncthreads();
    const bool fast = s_fast != 0;

    if ((int)blockIdx.x < nblkC) {
        if (fast) return;                         // prefix fills quotas: no-op
        iou_block(S, rois, gts, N, M, NBLK_A + (int)blockIdx.x, key, bestgt, grpPk);
        __threadfence();                          // release (slow path only)
        __syncthreads();
        if (tid == 0) atomicAdd(cnt, 1);
        return;
    }

    // ======================= finish block (blockIdx.x == nblkC) ==================
    if (!fast) {
        if (tid == 0) { while (atomicAdd(cnt, 0) < nblkC) { } }  // never on bench input
        __syncthreads();
        __threadfence();                          // acquire
    }

    // ---- totals ----
    if (fast) {
        if (tid == 0) { s_tp = MAXPOS; s_tn = RPI - MAXPOS; }
    } else {
        int sumP = 0, sumN = 0;
        for (int g = tid; g < ngroups; g += 256) {
            int v = grpPk[g];
            sumP += v >> 16;
            sumN += v & 0xFFFF;
        }
#pragma unroll
        for (int o = 32; o > 0; o >>= 1) {
            sumP += __shfl_down(sumP, o);
            sumN += __shfl_down(sumN, o);
        }
        if (l == 0) { redP[w] = sumP; redN[w] = sumN; }
        __syncthreads();
        if (tid == 0) {
            int totP = redP[0] + redP[1] + redP[2] + redP[3];
            int totN = redN[0] + redN[1] + redN[2] + redN[3];
            int tp  = totP < MAXPOS ? totP : MAXPOS;
            int rem = RPI - tp;
            s_tp = tp;
            s_tn = totN < rem ? totN : rem;
        }
    }
    slot[tid] = -1;
    __syncthreads();
    const int tp = s_tp, tn = s_tn;

    // ---- select: wave 0 walks groups in order, prefetching next group ----
    if (w == 0) {
        int cp = 0, cn = 0;
        int kc = (l < N) ? (int)key[l] : 2;           // group 0 prefetched
        for (int g = 0; g < ngroups && (cp < tp || cn < tn); ++g) {
            int i2 = (g + 1) * 64 + l;
            int kn = (g + 1 < ngroups && i2 < N) ? (int)key[i2] : 2;
            unsigned long long mp = __ballot(kc == 0);
            unsigned long long mn = __ballot(kc == 1);
            unsigned long long lt = (1ull << l) - 1ull;
            int i = g * 64 + l;
            if (kc == 0) {
                int rr = cp + __popcll(mp & lt);
                if (rr < tp) slot[rr] = i;
            } else if (kc == 1) {
                int rr = cn + __popcll(mn & lt);
                if (rr < tn) slot[tp + rr] = i;
            }
            cp += __popcll(mp); cn += __popcll(mn);
            kc = kn;
        }
    }
    __syncthreads();

    // ---- emit: deltas + label per row (256 threads = 256 rows) ----
    {
        int  roi   = slot[tid];
        bool valid = roi >= 0;
        bool ispos = valid && (tid < tp);
        float d0 = 0.f, d1 = 0.f, d2 = 0.f, d3 = 0.f;
        int lab = valid ? 0 : -1;                     // -1 => all-zero one-hot row
        if (ispos) {
            int gi    = (int)bestgt[roi];
            float4 b  = ((const float4*)rois)[roi];
            float4 gb = ((const float4*)gts)[gi];
            lab = labels[gi];
            float bh  = b.z - b.x,  bw  = b.w - b.y;
            float bcy = b.x + 0.5f * bh, bcx = b.y + 0.5f * bw;
            float gh  = gb.z - gb.x, gw  = gb.w - gb.y;
            float gcy = gb.x + 0.5f * gh, gcx = gb.y + 0.5f * gw;
            float bhs = (bh == 0.f) ? 1.f : bh;
            float bws = (bw == 0.f) ? 1.f : bw;
            float ghs = (gh <= 0.f) ? 1.f : gh;
            float gws = (gw <= 0.f) ? 1.f : gw;
            float dy = (gh == 0.f) ? 0.f : (gcy - bcy) / bhs;
            float dx = (gw == 0.f) ? 0.f : (gcx - bcx) / bws;
            float dh = (gh == 0.f) ? 0.f : logf(ghs / bhs);
            float dw = (gw == 0.f) ? 0.f : logf(gws / bws);
            d0 = dy / 0.1f; d1 = dx / 0.1f; d2 = dh / 0.2f; d3 = dw / 0.2f;
        }
        slab[tid] = lab;
        ((float4*)outD)[tid] = make_float4(d0, d1, d2, d3);
    }
    __syncthreads();

    // ---- one-hot: coalesced over 256*91 (91 iterations of 256 lanes) ----
    for (int idx = tid; idx < RPI * 91; idx += 256) {
        int rr = idx / 91;                 // compiler magic-mul
        int cc = idx - rr * 91;
        outH[idx] = (cc == slab[rr]) ? 1.0f : 0.0f;
    }
}

// ---------------- host launcher ----------------
extern "C" void kernel_launch(void* const* d_in, const int* in_sizes, int n_in,
                              void* d_out, int out_size, void* d_ws, size_t ws_size,
                              hipStream_t stream) {
    const float* rois   = (const float*)d_in[1];   // [1,N,4]
    const float* gts    = (const float*)d_in[2];   // [1,M,4]
    const int*   labels = (const int*)  d_in[3];   // [1,M]
    int N = in_sizes[1] / 4;
    int M = in_sizes[2] / 4;

    char* ws = (char*)d_ws;
    int*     cnt    = (int*)    (ws + WS_CNT);
    int*     grpPk  = (int*)    (ws + WS_GRPPK);
    int16_t* bestgt = (int16_t*)(ws + WS_BESTGT);
    uint8_t* key    = (uint8_t*)(ws + WS_KEY);

    int nblk    = (N + 127) / 128;
    int ngroups = (N + 63) / 64;
    int nblkA   = nblk < NBLK_A ? nblk : NBLK_A;
    int kgrp    = ngroups < 2 * nblkA ? ngroups : 2 * nblkA;
    int nblkC   = nblk - nblkA;
    if (nblkC < 0) nblkC = 0;

    float* outD = (float*)d_out;          // [1,256,4]
    float* outH = outD + RPI * 4;         // [1,256,91]

    // Node 1: exact IoU on the prefix (+ arms the slow-path arrival counter)
    iouA_kernel<<<nblkA, 256, 0, stream>>>(rois, gts, N, M, key, bestgt, grpPk, cnt);
    // Node 2: quota-gated rest-of-IoU + finish (last block)
    mega_kernel<<<nblkC + 1, 256, 0, stream>>>(rois, gts, labels, N, M,
                                               key, bestgt, grpPk, cnt,
                                               outD, outH, kgrp, nblkC, ngroups);
}

// Round 9
// 23.166 us; speedup vs baseline: 1.0703x; 1.0703x over previous
//
#include <hip/hip_runtime.h>
#include <cstdint>

// ---------------- problem constants ----------------
static constexpr int RPI    = 256;   // ROIS_PER_IMAGE
static constexpr int MAXPOS = 64;    // round(256*0.25)
static constexpr int MAX_GT = 256;   // LDS capacity for gt boxes (M=200)
static constexpr int MAXG   = 4096;  // max 64-ROI groups (N <= 262144)
static constexpr int NBLK_A = 32;    // phase-A blocks (128 ROIs each -> 64 groups)
static constexpr int NBF    = 64;    // node-2 worker blocks (grid-stride slow path)

// ---------------- workspace layout (bytes) ----------------
static constexpr size_t WS_CNT    = 0;                                  // int: slow-path arrivals
static constexpr size_t WS_GRPPK  = 64;                                 // packed (pos<<16|neg)
static constexpr size_t WS_BESTGT = WS_GRPPK + (size_t)MAXG * 4;        // int16 per ROI
static constexpr size_t WS_KEY    = WS_BESTGT + (size_t)262144 * 2;     // uint8 per ROI

// ---------------- shared IoU block body (R3/R6/R7/R8-proven, absmax 0) -----------
// Block = 256 thr = 4 waves, owns 128 ROIs (2/lane); each wave handles ITS
// quarter of the GT list; partials merged in segment order. Rational argmax
// tracking (bi,c1): r_c > r_b <=> I_c*c1_b > bi_b*S_c. Winner's IoU
// RECOMPUTED in exact reference op order, ONE IEEE divide -> bit-exact.
struct IouSmem {
    float4 sgt[MAX_GT];
    float  sarea[MAX_GT];
    float  sabe[MAX_GT];
    float  sbi[4][128];
    float  sc1[4][128];
    short  sbj[4][128];
};

__device__ __forceinline__ void stage_gt(
    IouSmem& S, const float* __restrict__ gts, int M)
{
#pragma clang fp contract(off)
    const int tid = threadIdx.x;
    for (int j = tid; j < M; j += 256) {
        float4 g = ((const float4*)gts)[j];
        S.sgt[j] = g;
        float a = (g.z - g.x) * (g.w - g.y);   // ref op order
        S.sarea[j] = a;
        S.sabe[j]  = a + 1e-7f;
    }
    __syncthreads();
}

// GT must already be staged. Includes the trailing __syncthreads so the smem
// partial arrays can be reused by the next tile.
__device__ __forceinline__ void iou_tile(
    IouSmem& S, const float* __restrict__ rois,
    int N, int M, int blk,
    uint8_t* __restrict__ key, int16_t* __restrict__ bestgt,
    int* __restrict__ grpPk)
{
#pragma clang fp contract(off)
    const int tid = threadIdx.x;
    const int w = tid >> 6, l = tid & 63;
    const int base = blk * 128;
    const int r0 = base + l, r1 = r0 + 64;
    const float4 zb = make_float4(0.f, 0.f, 0.f, 0.f);
    float4 b0 = (r0 < N) ? ((const float4*)rois)[r0] : zb;
    float4 b1 = (r1 < N) ? ((const float4*)rois)[r1] : zb;
    float aA0 = (b0.z - b0.x) * (b0.w - b0.y);
    float aA1 = (b1.z - b1.x) * (b1.w - b1.y);

    const int seglen = (M + 3) >> 2;
    const int j0 = w * seglen, j1 = min(M, j0 + seglen);

    float bi0 = -1.f, c10 = 0.f, bi1 = -1.f, c11 = 0.f;   // first j always wins
    int   bj0 = j0,   bj1 = j0;

    float4 g  = S.sgt[j0];               // sized-256 arrays: j+1 read in-bounds
    float  ae = S.sabe[j0];
#pragma unroll 2
    for (int j = j0; j < j1; ++j) {
        float4 gn = S.sgt[j + 1];        // register prefetch
        float  an = S.sabe[j + 1];
        {
            float ih = fmaxf(fminf(b0.z, g.z) - fmaxf(b0.x, g.x), 0.f);
            float iw = fmaxf(fminf(b0.w, g.w) - fmaxf(b0.y, g.y), 0.f);
            float inter = ih * iw;
            float Sx = aA0 + ae;
            bool  s = (inter * c10) > (bi0 * Sx);
            bi0 = s ? inter : bi0;  c10 = s ? Sx : c10;  bj0 = s ? j : bj0;
        }
        {
            float ih = fmaxf(fminf(b1.z, g.z) - fmaxf(b1.x, g.x), 0.f);
            float iw = fmaxf(fminf(b1.w, g.w) - fmaxf(b1.y, g.y), 0.f);
            float inter = ih * iw;
            float Sx = aA1 + ae;
            bool  s = (inter * c11) > (bi1 * Sx);
            bi1 = s ? inter : bi1;  c11 = s ? Sx : c11;  bj1 = s ? j : bj1;
        }
        g = gn; ae = an;
    }
    S.sbi[w][l]      = bi0;  S.sc1[w][l]      = c10;  S.sbj[w][l]      = (short)bj0;
    S.sbi[w][64 + l] = bi1;  S.sc1[w][64 + l] = c11;  S.sbj[w][64 + l] = (short)bj1;
    __syncthreads();

    if (tid < 128) {
        float BI = S.sbi[0][tid], C1 = S.sc1[0][tid];
        int   BJ = (int)S.sbj[0][tid];
#pragma unroll
        for (int s2 = 1; s2 < 4; ++s2) {
            float ci = S.sbi[s2][tid], cc = S.sc1[s2][tid];
            bool sel = (ci * C1) > (BI * cc);
            BI = sel ? ci : BI;  C1 = sel ? cc : C1;
            BJ = sel ? (int)S.sbj[s2][tid] : BJ;
        }
        float4 bb = (tid < 64) ? b0 : b1;   // thread tid holds box of ROI base+tid
        float  aa = (tid < 64) ? aA0 : aA1;
        int r = base + tid;
        int kk = 2;
        if (r < N) {
            float4 gg = S.sgt[BJ];
            float  ab = S.sarea[BJ];
            float ih = fmaxf(fminf(bb.z, gg.z) - fmaxf(bb.x, gg.x), 0.f);
            float iw = fmaxf(fminf(bb.w, gg.w) - fmaxf(bb.y, gg.y), 0.f);
            float inter = ih * iw;
            float u1 = ((aa + ab) - inter) + 1e-7f;   // exact ref op order
            float q  = inter / u1;                    // the ONLY division
            kk = (q > 0.5f) ? 0 : ((q < 0.5f && q > 0.1f) ? 1 : 2);
            key[r]    = (uint8_t)kk;
            bestgt[r] = (int16_t)BJ;
        }
        unsigned long long mp = __ballot(kk == 0);
        unsigned long long mn = __ballot(kk == 1);
        if (l == 0)
            grpPk[blk * 2 + w] = (__popcll(mp) << 16) | __popcll(mn);
    }
    __syncthreads();                      // smem reusable by next tile
}

// ---------------- kernel 1: phase A — exact IoU on the first 4096 ROIs -----------
__global__ __launch_bounds__(256) void iouA_kernel(
    const float* __restrict__ rois, const float* __restrict__ gts,
    int N, int M,
    uint8_t* __restrict__ key, int16_t* __restrict__ bestgt,
    int* __restrict__ grpPk, int* __restrict__ cnt)
{
    __shared__ IouSmem S;
    if (blockIdx.x == 0 && threadIdx.x == 0) cnt[0] = 0;  // arm slow-path counter
    stage_gt(S, gts, M);
    iou_tile(S, rois, N, M, (int)blockIdx.x, key, bestgt, grpPk);
}

// ---------------- kernel 2: gated grid-stride phase C + finish -------------------
// Grid = nWork+1 blocks (nWork <= NBF). Every block inlines the quota check
// over the phase-A prefix: if the prefix holds >= MAXPOS positives and
// >= RPI-MAXPOS negatives, tp/tn saturate exactly and all selected ROIs are
// in the prefix -> worker blocks exit after ONE dispatch round (~64 blocks,
// not 1531), finish block needs no sibling data. Slow path (never taken on
// this input): workers grid-stride the remaining tiles (GT staged once per
// block), release-fence + arrival atomic; finish spins then full reduction.
__global__ __launch_bounds__(256) void gated_kernel(
    const float* __restrict__ rois, const float* __restrict__ gts,
    const int* __restrict__ labels,
    int N, int M,
    uint8_t* __restrict__ key, int16_t* __restrict__ bestgt,
    int* __restrict__ grpPk, int* __restrict__ cnt,
    float* __restrict__ outD, float* __restrict__ outH,
    int kgrp, int nblkC, int nWork, int ngroups)
{
#pragma clang fp contract(off)
    __shared__ IouSmem S;
    __shared__ int slot[RPI], slab[RPI];
    __shared__ int redP[4], redN[4];
    __shared__ int s_fast, s_tp, s_tn;

    const int tid = threadIdx.x, w = tid >> 6, l = tid & 63;

    // ---- inline quota check (all blocks; wave 0 computes, LDS broadcast) ----
    if (w == 0) {
        int v = (l < kgrp) ? grpPk[l] : 0;
        int p = v >> 16, n = v & 0xFFFF;
#pragma unroll
        for (int o = 1; o < 64; o <<= 1) {
            p += __shfl_xor(p, o);
            n += __shfl_xor(n, o);
        }
        if (l == 0) s_fast = (p >= MAXPOS && n >= RPI - MAXPOS) ? 1 : 0;
    }
    __syncthreads();
    const bool fast = s_fast != 0;

    if ((int)blockIdx.x < nWork) {
        if (fast) return;                         // prefix fills quotas: no-op
        // ---- slow path: grid-stride over remaining tiles, GT staged once ----
        stage_gt(S, gts, M);
        for (int t = (int)blockIdx.x; t < nblkC; t += nWork)
            iou_tile(S, rois, N, M, NBLK_A + t, key, bestgt, grpPk);
        __threadfence();                          // release
        __syncthreads();
        if (tid == 0) atomicAdd(cnt, 1);
        return;
    }

    // ======================= finish block (blockIdx.x == nWork) ==================
    if (!fast) {
        if (tid == 0) { while (atomicAdd(cnt, 0) < nWork) { } }  // never on bench input
        __syncthreads();
        __threadfence();                          // acquire
    }

    // ---- totals ----
    if (fast) {
        if (tid == 0) { s_tp = MAXPOS; s_tn = RPI - MAXPOS; }
    } else {
        int sumP = 0, sumN = 0;
        for (int g = tid; g < ngroups; g += 256) {
            int v = grpPk[g];
            sumP += v >> 16;
            sumN += v & 0xFFFF;
        }
#pragma unroll
        for (int o = 32; o > 0; o >>= 1) {
            sumP += __shfl_down(sumP, o);
            sumN += __shfl_down(sumN, o);
        }
        if (l == 0) { redP[w] = sumP; redN[w] = sumN; }
        __syncthreads();
        if (tid == 0) {
            int totP = redP[0] + redP[1] + redP[2] + redP[3];
            int totN = redN[0] + redN[1] + redN[2] + redN[3];
            int tp  = totP < MAXPOS ? totP : MAXPOS;
            int rem = RPI - tp;
            s_tp = tp;
            s_tn = totN < rem ? totN : rem;
        }
    }
    slot[tid] = -1;
    __syncthreads();
    const int tp = s_tp, tn = s_tn;

    // ---- select: wave 0 walks groups in order, prefetching next group ----
    if (w == 0) {
        int cp = 0, cn = 0;
        int kc = (l < N) ? (int)key[l] : 2;           // group 0 prefetched
        for (int g = 0; g < ngroups && (cp < tp || cn < tn); ++g) {
            int i2 = (g + 1) * 64 + l;
            int kn = (g + 1 < ngroups && i2 < N) ? (int)key[i2] : 2;
            unsigned long long mp = __ballot(kc == 0);
            unsigned long long mn = __ballot(kc == 1);
            unsigned long long lt = (1ull << l) - 1ull;
            int i = g * 64 + l;
            if (kc == 0) {
                int rr = cp + __popcll(mp & lt);
                if (rr < tp) slot[rr] = i;
            } else if (kc == 1) {
                int rr = cn + __popcll(mn & lt);
                if (rr < tn) slot[tp + rr] = i;
            }
            cp += __popcll(mp); cn += __popcll(mn);
            kc = kn;
        }
    }
    __syncthreads();

    // ---- emit: deltas + label per row (256 threads = 256 rows) ----
    {
        int  roi   = slot[tid];
        bool valid = roi >= 0;
        bool ispos = valid && (tid < tp);
        float d0 = 0.f, d1 = 0.f, d2 = 0.f, d3 = 0.f;
        int lab = valid ? 0 : -1;                     // -1 => all-zero one-hot row
        if (ispos) {
            int gi    = (int)bestgt[roi];
            float4 b  = ((const float4*)rois)[roi];
            float4 gb = ((const float4*)gts)[gi];
            lab = labels[gi];
            float bh  = b.z - b.x,  bw  = b.w - b.y;
            float bcy = b.x + 0.5f * bh, bcx = b.y + 0.5f * bw;
            float gh  = gb.z - gb.x, gw  = gb.w - gb.y;
            float gcy = gb.x + 0.5f * gh, gcx = gb.y + 0.5f * gw;
            float bhs = (bh == 0.f) ? 1.f : bh;
            float bws = (bw == 0.f) ? 1.f : bw;
            float ghs = (gh <= 0.f) ? 1.f : gh;
            float gws = (gw <= 0.f) ? 1.f : gw;
            float dy = (gh == 0.f) ? 0.f : (gcy - bcy) / bhs;
            float dx = (gw == 0.f) ? 0.f : (gcx - bcx) / bws;
            float dh = (gh == 0.f) ? 0.f : logf(ghs / bhs);
            float dw = (gw == 0.f) ? 0.f : logf(gws / bws);
            d0 = dy / 0.1f; d1 = dx / 0.1f; d2 = dh / 0.2f; d3 = dw / 0.2f;
        }
        slab[tid] = lab;
        ((float4*)outD)[tid] = make_float4(d0, d1, d2, d3);
    }
    __syncthreads();

    // ---- one-hot: coalesced over 256*91 (91 iterations of 256 lanes) ----
    for (int idx = tid; idx < RPI * 91; idx += 256) {
        int rr = idx / 91;                 // compiler magic-mul
        int cc = idx - rr * 91;
        outH[idx] = (cc == slab[rr]) ? 1.0f : 0.0f;
    }
}

// ---------------- host launcher ----------------
extern "C" void kernel_launch(void* const* d_in, const int* in_sizes, int n_in,
                              void* d_out, int out_size, void* d_ws, size_t ws_size,
                              hipStream_t stream) {
    const float* rois   = (const float*)d_in[1];   // [1,N,4]
    const float* gts    = (const float*)d_in[2];   // [1,M,4]
    const int*   labels = (const int*)  d_in[3];   // [1,M]
    int N = in_sizes[1] / 4;
    int M = in_sizes[2] / 4;

    char* ws = (char*)d_ws;
    int*     cnt    = (int*)    (ws + WS_CNT);
    int*     grpPk  = (int*)    (ws + WS_GRPPK);
    int16_t* bestgt = (int16_t*)(ws + WS_BESTGT);
    uint8_t* key    = (uint8_t*)(ws + WS_KEY);

    int nblk    = (N + 127) / 128;
    int ngroups = (N + 63) / 64;
    int nblkA   = nblk < NBLK_A ? nblk : NBLK_A;
    int kgrp    = ngroups < 2 * nblkA ? ngroups : 2 * nblkA;
    int nblkC   = nblk - nblkA;
    if (nblkC < 0) nblkC = 0;
    int nWork   = nblkC < NBF ? nblkC : NBF;       // worker blocks (0 if no phase C)

    float* outD = (float*)d_out;          // [1,256,4]
    float* outH = outD + RPI * 4;         // [1,256,91]

    // Node 1: exact IoU on the prefix (+ arms the slow-path arrival counter)
    iouA_kernel<<<nblkA, 256, 0, stream>>>(rois, gts, N, M, key, bestgt, grpPk, cnt);
    // Node 2: quota-gated grid-stride rest-of-IoU + finish (last block)
    gated_kernel<<<nWork + 1, 256, 0, stream>>>(rois, gts, labels, N, M,
                                                key, bestgt, grpPk, cnt,
                                                outD, outH, kgrp, nblkC, nWork, ngroups);
}

// Round 10
// 18.176 us; speedup vs baseline: 1.3641x; 1.2746x over previous
//
#include <hip/hip_runtime.h>
#include <cstdint>

// ---------------- problem constants ----------------
static constexpr int RPI    = 256;   // ROIS_PER_IMAGE
static constexpr int MAXPOS = 64;    // round(256*0.25)
static constexpr int MAXNEG = RPI - MAXPOS;   // 192 (fast-path quota)
static constexpr int MAX_GT = 256;   // LDS capacity for gt boxes (M=200)
static constexpr int MAXG   = 4096;  // max 64-ROI groups (N <= 262144)
static constexpr int NBLK_A = 32;    // phase-A blocks (128 ROIs each -> 64 groups)
static constexpr int NBF    = 64;    // node-2 worker blocks

// ---------------- workspace layout (bytes) ----------------
static constexpr size_t WS_CNT    = 0;                                  // int: slow-path arrivals
static constexpr size_t WS_GRPPK  = 64;                                 // packed (pos<<16|neg)
static constexpr size_t WS_BESTGT = WS_GRPPK + (size_t)MAXG * 4;        // int16 per ROI
static constexpr size_t WS_KEY    = WS_BESTGT + (size_t)262144 * 2;     // uint8 per ROI (16B-aligned)

// ---------------- shared IoU block body (R3..R9-proven, absmax 0) ----------------
struct IouSmem {
    float4 sgt[MAX_GT];
    float  sarea[MAX_GT];
    float  sabe[MAX_GT];
    float  sbi[4][128];
    float  sc1[4][128];
    short  sbj[4][128];
};

__device__ __forceinline__ void stage_gt(
    IouSmem& S, const float* __restrict__ gts, int M)
{
#pragma clang fp contract(off)
    const int tid = threadIdx.x;
    for (int j = tid; j < M; j += 256) {
        float4 g = ((const float4*)gts)[j];
        S.sgt[j] = g;
        float a = (g.z - g.x) * (g.w - g.y);   // ref op order
        S.sarea[j] = a;
        S.sabe[j]  = a + 1e-7f;
    }
    __syncthreads();
}

__device__ __forceinline__ void iou_tile(
    IouSmem& S, const float* __restrict__ rois,
    int N, int M, int blk,
    uint8_t* __restrict__ key, int16_t* __restrict__ bestgt,
    int* __restrict__ grpPk)
{
#pragma clang fp contract(off)
    const int tid = threadIdx.x;
    const int w = tid >> 6, l = tid & 63;
    const int base = blk * 128;
    const int r0 = base + l, r1 = r0 + 64;
    const float4 zb = make_float4(0.f, 0.f, 0.f, 0.f);
    float4 b0 = (r0 < N) ? ((const float4*)rois)[r0] : zb;
    float4 b1 = (r1 < N) ? ((const float4*)rois)[r1] : zb;
    float aA0 = (b0.z - b0.x) * (b0.w - b0.y);
    float aA1 = (b1.z - b1.x) * (b1.w - b1.y);

    const int seglen = (M + 3) >> 2;
    const int j0 = w * seglen, j1 = min(M, j0 + seglen);

    float bi0 = -1.f, c10 = 0.f, bi1 = -1.f, c11 = 0.f;   // first j always wins
    int   bj0 = j0,   bj1 = j0;

    float4 g  = S.sgt[j0];               // sized-256 arrays: j+1 read in-bounds
    float  ae = S.sabe[j0];
#pragma unroll 2
    for (int j = j0; j < j1; ++j) {
        float4 gn = S.sgt[j + 1];        // register prefetch
        float  an = S.sabe[j + 1];
        {
            float ih = fmaxf(fminf(b0.z, g.z) - fmaxf(b0.x, g.x), 0.f);
            float iw = fmaxf(fminf(b0.w, g.w) - fmaxf(b0.y, g.y), 0.f);
            float inter = ih * iw;
            float Sx = aA0 + ae;
            bool  s = (inter * c10) > (bi0 * Sx);
            bi0 = s ? inter : bi0;  c10 = s ? Sx : c10;  bj0 = s ? j : bj0;
        }
        {
            float ih = fmaxf(fminf(b1.z, g.z) - fmaxf(b1.x, g.x), 0.f);
            float iw = fmaxf(fminf(b1.w, g.w) - fmaxf(b1.y, g.y), 0.f);
            float inter = ih * iw;
            float Sx = aA1 + ae;
            bool  s = (inter * c11) > (bi1 * Sx);
            bi1 = s ? inter : bi1;  c11 = s ? Sx : c11;  bj1 = s ? j : bj1;
        }
        g = gn; ae = an;
    }
    S.sbi[w][l]      = bi0;  S.sc1[w][l]      = c10;  S.sbj[w][l]      = (short)bj0;
    S.sbi[w][64 + l] = bi1;  S.sc1[w][64 + l] = c11;  S.sbj[w][64 + l] = (short)bj1;
    __syncthreads();

    if (tid < 128) {
        float BI = S.sbi[0][tid], C1 = S.sc1[0][tid];
        int   BJ = (int)S.sbj[0][tid];
#pragma unroll
        for (int s2 = 1; s2 < 4; ++s2) {
            float ci = S.sbi[s2][tid], cc = S.sc1[s2][tid];
            bool sel = (ci * C1) > (BI * cc);
            BI = sel ? ci : BI;  C1 = sel ? cc : C1;
            BJ = sel ? (int)S.sbj[s2][tid] : BJ;
        }
        float4 bb = (tid < 64) ? b0 : b1;   // thread tid holds box of ROI base+tid
        float  aa = (tid < 64) ? aA0 : aA1;
        int r = base + tid;
        int kk = 2;
        if (r < N) {
            float4 gg = S.sgt[BJ];
            float  ab = S.sarea[BJ];
            float ih = fmaxf(fminf(bb.z, gg.z) - fmaxf(bb.x, gg.x), 0.f);
            float iw = fmaxf(fminf(bb.w, gg.w) - fmaxf(bb.y, gg.y), 0.f);
            float inter = ih * iw;
            float u1 = ((aa + ab) - inter) + 1e-7f;   // exact ref op order
            float q  = inter / u1;                    // the ONLY division
            kk = (q > 0.5f) ? 0 : ((q < 0.5f && q > 0.1f) ? 1 : 2);
            key[r]    = (uint8_t)kk;
            bestgt[r] = (int16_t)BJ;
        }
        unsigned long long mp = __ballot(kk == 0);
        unsigned long long mn = __ballot(kk == 1);
        if (l == 0)
            grpPk[blk * 2 + w] = (__popcll(mp) << 16) | __popcll(mn);
    }
    __syncthreads();                      // smem reusable by next tile
}

// ---------------- deltas + one-hot for ONE output row, one wave ------------------
__device__ __forceinline__ void emit_row(
    int row, int roi, int tp, int l,
    const float* __restrict__ rois, const float* __restrict__ gts,
    const int* __restrict__ labels, const int16_t* __restrict__ bestgt,
    float* __restrict__ outD, float* __restrict__ outH)
{
#pragma clang fp contract(off)
    bool valid = roi >= 0;
    bool ispos = valid && (row < tp);
    float d0 = 0.f, d1 = 0.f, d2 = 0.f, d3 = 0.f;
    int lab = valid ? 0 : -1;                     // -1 => all-zero one-hot row
    if (ispos) {
        int gi    = (int)bestgt[roi];
        float4 b  = ((const float4*)rois)[roi];
        float4 gb = ((const float4*)gts)[gi];
        lab = labels[gi];
        float bh  = b.z - b.x,  bw  = b.w - b.y;
        float bcy = b.x + 0.5f * bh, bcx = b.y + 0.5f * bw;
        float gh  = gb.z - gb.x, gw  = gb.w - gb.y;
        float gcy = gb.x + 0.5f * gh, gcx = gb.y + 0.5f * gw;
        float bhs = (bh == 0.f) ? 1.f : bh;
        float bws = (bw == 0.f) ? 1.f : bw;
        float ghs = (gh <= 0.f) ? 1.f : gh;
        float gws = (gw <= 0.f) ? 1.f : gw;
        float dy = (gh == 0.f) ? 0.f : (gcy - bcy) / bhs;
        float dx = (gw == 0.f) ? 0.f : (gcx - bcx) / bws;
        float dh = (gh == 0.f) ? 0.f : logf(ghs / bhs);
        float dw = (gw == 0.f) ? 0.f : logf(gws / bws);
        d0 = dy / 0.1f; d1 = dx / 0.1f; d2 = dh / 0.2f; d3 = dw / 0.2f;
    }
    if (l == 0) ((float4*)outD)[row] = make_float4(d0, d1, d2, d3);
    outH[row * 91 + l] = (l == lab) ? 1.0f : 0.0f;            // cc = 0..63
    if (l < 27) outH[row * 91 + 64 + l] = ((64 + l) == lab) ? 1.0f : 0.0f;  // 64..90
}

// ---------------- kernel 1: phase A — exact IoU on the first 4096 ROIs -----------
__global__ __launch_bounds__(256) void iouA_kernel(
    const float* __restrict__ rois, const float* __restrict__ gts,
    int N, int M,
    uint8_t* __restrict__ key, int16_t* __restrict__ bestgt,
    int* __restrict__ grpPk, int* __restrict__ cnt)
{
    __shared__ IouSmem S;
    if (blockIdx.x == 0 && threadIdx.x == 0) cnt[0] = 0;  // arm slow-path counter
    stage_gt(S, gts, M);
    iou_tile(S, rois, N, M, (int)blockIdx.x, key, bestgt, grpPk);
}

// ---------------- kernel 2: gated finish ----------------------------------------
// FAST PATH (quota provably filled by the 4096-ROI prefix): tp/tn saturate to
// 64/192 exactly and all selected ROIs are in the prefix. Selection becomes a
// PARALLEL prefix-scan: each block redundantly loads the 4096 prefix keys
// (16/thread, one coalesced uint4 round), 256-thread exclusive scan of
// pos/neg counts, direct slot writes (== cumsum take-first-k, bit-exact).
// All gridDim blocks then emit DISJOINT output rows (4/block) in parallel.
// SLOW PATH (never on this input): R9 unchanged — workers grid-stride IoU,
// release fence + arrival atomic; last block does totals + serial walk + emit.
__global__ __launch_bounds__(256) void gated_kernel(
    const float* __restrict__ rois, const float* __restrict__ gts,
    const int* __restrict__ labels,
    int N, int M,
    uint8_t* __restrict__ key, int16_t* __restrict__ bestgt,
    int* __restrict__ grpPk, int* __restrict__ cnt,
    float* __restrict__ outD, float* __restrict__ outH,
    int kgrp, int nblkC, int nWork, int ngroups)
{
#pragma clang fp contract(off)
    __shared__ IouSmem S;
    __shared__ int slot[RPI], slab[RPI];
    __shared__ int redP[4], redN[4];
    __shared__ int wTotP[4], wTotN[4];
    __shared__ int s_fast, s_tp, s_tn;

    const int tid = threadIdx.x, w = tid >> 6, l = tid & 63;

    // ---- inline quota check (all blocks; wave 0 computes, LDS broadcast) ----
    if (tid < RPI) slot[tid] = -1;
    if (w == 0) {
        int v = (l < kgrp) ? grpPk[l] : 0;
        int p = v >> 16, n = v & 0xFFFF;
#pragma unroll
        for (int o = 1; o < 64; o <<= 1) {
            p += __shfl_xor(p, o);
            n += __shfl_xor(n, o);
        }
        if (l == 0) s_fast = (p >= MAXPOS && n >= MAXNEG) ? 1 : 0;
    }
    __syncthreads();
    const bool fast = s_fast != 0;

    if (fast) {
        // ================= parallel select over the 4096-key prefix =================
        const int nk = kgrp * 4;             // active threads (16 keys each)
        int kc[16];
        int p = 0, n = 0;
        if (tid < nk) {
            uint4 kv = ((const uint4*)key)[tid];
            unsigned wd[4] = { kv.x, kv.y, kv.z, kv.w };
            const int i0 = tid * 16;
#pragma unroll
            for (int x = 0; x < 4; ++x)
#pragma unroll
                for (int b = 0; b < 4; ++b) {
                    int i = 4 * x + b;
                    int k = (int)((wd[x] >> (8 * b)) & 0xFF);
                    kc[i] = (i0 + i < N) ? k : 2;
                    p += (kc[i] == 0);
                    n += (kc[i] == 1);
                }
        } else {
#pragma unroll
            for (int i = 0; i < 16; ++i) kc[i] = 2;
        }
        // ---- 256-thread exclusive scan of (p, n) ----
        int ip = p, in_ = n;
#pragma unroll
        for (int o = 1; o < 64; o <<= 1) {
            int up = __shfl_up(ip, o), un = __shfl_up(in_, o);
            if (l >= o) { ip += up; in_ += un; }
        }
        if (l == 63) { wTotP[w] = ip; wTotN[w] = in_; }
        __syncthreads();
        int bp = 0, bn = 0;
        for (int x = 0; x < w; ++x) { bp += wTotP[x]; bn += wTotN[x]; }
        int rp = bp + ip - p;                // exclusive global pos rank
        int rn = bn + in_ - n;               // exclusive global neg rank
        // ---- direct slot writes (take-first-k) ----
        const int i0 = tid * 16;
#pragma unroll
        for (int i = 0; i < 16; ++i) {
            if (kc[i] == 0)      { if (rp < MAXPOS) slot[rp] = i0 + i; ++rp; }
            else if (kc[i] == 1) { if (rn < MAXNEG) slot[MAXPOS + rn] = i0 + i; ++rn; }
        }
        __syncthreads();
        // ---- emit: each block owns disjoint rows (4 per block, wave-per-row) ----
        const int stride = gridDim.x * 4;
        for (int row = (int)blockIdx.x * 4 + w; row < RPI; row += stride)
            emit_row(row, slot[row], MAXPOS, l, rois, gts, labels, bestgt, outD, outH);
        return;
    }

    // ========================== slow path (R9, unchanged) ========================
    if ((int)blockIdx.x < nWork) {
        stage_gt(S, gts, M);
        for (int t = (int)blockIdx.x; t < nblkC; t += nWork)
            iou_tile(S, rois, N, M, NBLK_A + t, key, bestgt, grpPk);
        __threadfence();                          // release
        __syncthreads();
        if (tid == 0) atomicAdd(cnt, 1);
        return;
    }
    if (tid == 0) { while (atomicAdd(cnt, 0) < nWork) { } }
    __syncthreads();
    __threadfence();                              // acquire

    {   // totals over all groups
        int sumP = 0, sumN = 0;
        for (int g = tid; g < ngroups; g += 256) {
            int v = grpPk[g];
            sumP += v >> 16;
            sumN += v & 0xFFFF;
        }
#pragma unroll
        for (int o = 32; o > 0; o >>= 1) {
            sumP += __shfl_down(sumP, o);
            sumN += __shfl_down(sumN, o);
        }
        if (l == 0) { redP[w] = sumP; redN[w] = sumN; }
        __syncthreads();
        if (tid == 0) {
            int totP = redP[0] + redP[1] + redP[2] + redP[3];
            int totN = redN[0] + redN[1] + redN[2] + redN[3];
            int tp  = totP < MAXPOS ? totP : MAXPOS;
            int rem = RPI - tp;
            s_tp = tp;
            s_tn = totN < rem ? totN : rem;
        }
    }
    __syncthreads();
    const int tp = s_tp, tn = s_tn;

    if (w == 0) {                                  // serial walk (slow path only)
        int cp = 0, cn = 0;
        int kc = (l < N) ? (int)key[l] : 2;
        for (int g = 0; g < ngroups && (cp < tp || cn < tn); ++g) {
            int i2 = (g + 1) * 64 + l;
            int kn = (g + 1 < ngroups && i2 < N) ? (int)key[i2] : 2;
            unsigned long long mp = __ballot(kc == 0);
            unsigned long long mn = __ballot(kc == 1);
            unsigned long long lt = (1ull << l) - 1ull;
            int i = g * 64 + l;
            if (kc == 0) {
                int rr = cp + __popcll(mp & lt);
                if (rr < tp) slot[rr] = i;
            } else if (kc == 1) {
                int rr = cn + __popcll(mn & lt);
                if (rr < tn) slot[tp + rr] = i;
            }
            cp += __popcll(mp); cn += __popcll(mn);
            kc = kn;
        }
    }
    __syncthreads();
    for (int row = w; row < RPI; row += 4)
        emit_row(row, slot[row], tp, l, rois, gts, labels, bestgt, outD, outH);
    (void)slab;
}

// ---------------- host launcher ----------------
extern "C" void kernel_launch(void* const* d_in, const int* in_sizes, int n_in,
                              void* d_out, int out_size, void* d_ws, size_t ws_size,
                              hipStream_t stream) {
    const float* rois   = (const float*)d_in[1];   // [1,N,4]
    const float* gts    = (const float*)d_in[2];   // [1,M,4]
    const int*   labels = (const int*)  d_in[3];   // [1,M]
    int N = in_sizes[1] / 4;
    int M = in_sizes[2] / 4;

    char* ws = (char*)d_ws;
    int*     cnt    = (int*)    (ws + WS_CNT);
    int*     grpPk  = (int*)    (ws + WS_GRPPK);
    int16_t* bestgt = (int16_t*)(ws + WS_BESTGT);
    uint8_t* key    = (uint8_t*)(ws + WS_KEY);

    int nblk    = (N + 127) / 128;
    int ngroups = (N + 63) / 64;
    int nblkA   = nblk < NBLK_A ? nblk : NBLK_A;
    int kgrp    = ngroups < 2 * nblkA ? ngroups : 2 * nblkA;
    int nblkC   = nblk - nblkA;
    if (nblkC < 0) nblkC = 0;
    int nWork   = nblkC < NBF ? nblkC : NBF;

    float* outD = (float*)d_out;          // [1,256,4]
    float* outH = outD + RPI * 4;         // [1,256,91]

    iouA_kernel<<<nblkA, 256, 0, stream>>>(rois, gts, N, M, key, bestgt, grpPk, cnt);
    gated_kernel<<<nWork + 1, 256, 0, stream>>>(rois, gts, labels, N, M,
                                                key, bestgt, grpPk, cnt,
                                                outD, outH, kgrp, nblkC, nWork, ngroups);
}

// Round 11
// 16.105 us; speedup vs baseline: 1.5395x; 1.1286x over previous
//
#include <hip/hip_runtime.h>
#include <cstdint>

// ---------------- problem constants ----------------
static constexpr int RPI    = 256;   // ROIS_PER_IMAGE
static constexpr int MAXPOS = 64;    // round(256*0.25)
static constexpr int MAXNEG = RPI - MAXPOS;   // 192 (fast-path quota)
static constexpr int MAX_GT = 256;   // LDS capacity for gt boxes (M=200)
static constexpr int MAXG   = 4096;  // max 64-ROI groups (N <= 262144)
static constexpr int NBLK_A = 64;    // phase-A blocks (64 ROIs each -> 64 groups = 4096 ROIs)
static constexpr int NBF    = 64;    // node-2 worker blocks

// ---------------- workspace layout (bytes) ----------------
static constexpr size_t WS_CNT    = 0;                                  // int: slow-path arrivals
static constexpr size_t WS_GRPPK  = 64;                                 // packed (pos<<16|neg), per 64-ROI group
static constexpr size_t WS_BESTGT = WS_GRPPK + (size_t)MAXG * 4;        // int16 per ROI
static constexpr size_t WS_KEY    = WS_BESTGT + (size_t)262144 * 2;     // uint8 per ROI (16B-aligned)

// ---------------- shared IoU tile body (R3..R10-proven math, absmax 0) -----------
// NEW tiling: block = 256 thr = 4 waves, owns 64 ROIs (1/lane); each wave
// processes all 64 ROIs against ITS quarter of the GT list (seglen ~50);
// prefetch DEPTH 2 hides the ~120-cyc LDS latency (per-iter issue is only
// ~50 cyc now). Rational argmax tracking (bi,c1): r_c > r_b <=> I_c*c1_b >
// bi_b*S_c. Winner's IoU RECOMPUTED in exact reference op order, ONE IEEE
// divide -> thresholds bit-exact.
struct IouSmem {
    float4 sgt[MAX_GT];
    float  sarea[MAX_GT];
    float  sabe[MAX_GT];
    float  sbi[4][64];
    float  sc1[4][64];
    short  sbj[4][64];
};

__device__ __forceinline__ void stage_gt(
    IouSmem& S, const float* __restrict__ gts, int M)
{
#pragma clang fp contract(off)
    const int tid = threadIdx.x;
    for (int j = tid; j < M; j += 256) {
        float4 g = ((const float4*)gts)[j];
        S.sgt[j] = g;
        float a = (g.z - g.x) * (g.w - g.y);   // ref op order
        S.sarea[j] = a;
        S.sabe[j]  = a + 1e-7f;
    }
    __syncthreads();
}

// GT must already be staged; trailing __syncthreads so smem is tile-reusable.
__device__ __forceinline__ void iou_tile(
    IouSmem& S, const float* __restrict__ rois,
    int N, int M, int blk,
    uint8_t* __restrict__ key, int16_t* __restrict__ bestgt,
    int* __restrict__ grpPk)
{
#pragma clang fp contract(off)
    const int tid = threadIdx.x;
    const int w = tid >> 6, l = tid & 63;
    const int base = blk * 64;
    const int r = base + l;
    const float4 zb = make_float4(0.f, 0.f, 0.f, 0.f);
    float4 b = (r < N) ? ((const float4*)rois)[r] : zb;
    float aA = (b.z - b.x) * (b.w - b.y);

    const int seglen = (M + 3) >> 2;
    const int j0 = w * seglen, j1 = min(M, j0 + seglen);

    float bi = -1.f, c1 = 0.f;           // first j always wins (0 > -S)
    int   bj = j0;

    // prefetch depth 2 (arrays sized 256; j+2 <= M+1 <= 255 stays in-bounds)
    float4 g0 = S.sgt[j0],     g1 = S.sgt[j0 + 1];
    float  a0 = S.sabe[j0],    a1 = S.sabe[j0 + 1];
#pragma unroll 2
    for (int j = j0; j < j1; ++j) {
        float4 gn = S.sgt[j + 2];
        float  an = S.sabe[j + 2];
        float ih = fmaxf(fminf(b.z, g0.z) - fmaxf(b.x, g0.x), 0.f);
        float iw = fmaxf(fminf(b.w, g0.w) - fmaxf(b.y, g0.y), 0.f);
        float inter = ih * iw;
        float Sx = aA + a0;
        bool  s = (inter * c1) > (bi * Sx);
        bi = s ? inter : bi;  c1 = s ? Sx : c1;  bj = s ? j : bj;
        g0 = g1; a0 = a1; g1 = gn; a1 = an;
    }
    S.sbi[w][l] = bi;  S.sc1[w][l] = c1;  S.sbj[w][l] = (short)bj;
    __syncthreads();

    if (tid < 64) {                      // wave 0: one ROI per lane
        float BI = S.sbi[0][tid], C1 = S.sc1[0][tid];
        int   BJ = (int)S.sbj[0][tid];
#pragma unroll
        for (int s2 = 1; s2 < 4; ++s2) {
            float ci = S.sbi[s2][tid], cc = S.sc1[s2][tid];
            bool sel = (ci * C1) > (BI * cc);
            BI = sel ? ci : BI;  C1 = sel ? cc : C1;
            BJ = sel ? (int)S.sbj[s2][tid] : BJ;
        }
        int rr = base + tid;
        int kk = 2;
        if (rr < N) {
            // lane tid holds box b of ROI base+tid (w==0 path loaded it)
            float4 gg = S.sgt[BJ];
            float  ab = S.sarea[BJ];
            float ih = fmaxf(fminf(b.z, gg.z) - fmaxf(b.x, gg.x), 0.f);
            float iw = fmaxf(fminf(b.w, gg.w) - fmaxf(b.y, gg.y), 0.f);
            float inter = ih * iw;
            float u1 = ((aA + ab) - inter) + 1e-7f;   // exact ref op order
            float q  = inter / u1;                    // the ONLY division
            kk = (q > 0.5f) ? 0 : ((q < 0.5f && q > 0.1f) ? 1 : 2);
            key[rr]    = (uint8_t)kk;
            bestgt[rr] = (int16_t)BJ;
        }
        unsigned long long mp = __ballot(kk == 0);
        unsigned long long mn = __ballot(kk == 1);
        if (tid == 0)
            grpPk[blk] = (__popcll(mp) << 16) | __popcll(mn);
    }
    __syncthreads();                     // smem reusable by next tile
}

// ---------------- deltas + one-hot for ONE output row, one wave ------------------
__device__ __forceinline__ void emit_row(
    int row, int roi, int tp, int l,
    const float* __restrict__ rois, const float* __restrict__ gts,
    const int* __restrict__ labels, const int16_t* __restrict__ bestgt,
    float* __restrict__ outD, float* __restrict__ outH)
{
#pragma clang fp contract(off)
    bool valid = roi >= 0;
    bool ispos = valid && (row < tp);
    float d0 = 0.f, d1 = 0.f, d2 = 0.f, d3 = 0.f;
    int lab = valid ? 0 : -1;                     // -1 => all-zero one-hot row
    if (ispos) {
        int gi    = (int)bestgt[roi];
        float4 b  = ((const float4*)rois)[roi];
        float4 gb = ((const float4*)gts)[gi];
        lab = labels[gi];
        float bh  = b.z - b.x,  bw  = b.w - b.y;
        float bcy = b.x + 0.5f * bh, bcx = b.y + 0.5f * bw;
        float gh  = gb.z - gb.x, gw  = gb.w - gb.y;
        float gcy = gb.x + 0.5f * gh, gcx = gb.y + 0.5f * gw;
        float bhs = (bh == 0.f) ? 1.f : bh;
        float bws = (bw == 0.f) ? 1.f : bw;
        float ghs = (gh <= 0.f) ? 1.f : gh;
        float gws = (gw <= 0.f) ? 1.f : gw;
        float dy = (gh == 0.f) ? 0.f : (gcy - bcy) / bhs;
        float dx = (gw == 0.f) ? 0.f : (gcx - bcx) / bws;
        float dh = (gh == 0.f) ? 0.f : logf(ghs / bhs);
        float dw = (gw == 0.f) ? 0.f : logf(gws / bws);
        d0 = dy / 0.1f; d1 = dx / 0.1f; d2 = dh / 0.2f; d3 = dw / 0.2f;
    }
    if (l == 0) ((float4*)outD)[row] = make_float4(d0, d1, d2, d3);
    outH[row * 91 + l] = (l == lab) ? 1.0f : 0.0f;            // cc = 0..63
    if (l < 27) outH[row * 91 + 64 + l] = ((64 + l) == lab) ? 1.0f : 0.0f;  // 64..90
}

// ---------------- kernel 1: phase A — exact IoU on the first 4096 ROIs -----------
__global__ __launch_bounds__(256) void iouA_kernel(
    const float* __restrict__ rois, const float* __restrict__ gts,
    int N, int M,
    uint8_t* __restrict__ key, int16_t* __restrict__ bestgt,
    int* __restrict__ grpPk, int* __restrict__ cnt)
{
    __shared__ IouSmem S;
    if (blockIdx.x == 0 && threadIdx.x == 0) cnt[0] = 0;  // arm slow-path counter
    stage_gt(S, gts, M);
    iou_tile(S, rois, N, M, (int)blockIdx.x, key, bestgt, grpPk);
}

// ---------------- kernel 2: gated finish (R10-proven) ----------------------------
// FAST PATH: quota provably filled by the 4096-ROI prefix -> tp/tn saturate
// to 64/192 exactly; parallel prefix-scan select over the 4096 keys; all
// blocks emit disjoint rows. SLOW PATH (never on this input): workers
// grid-stride remaining 64-ROI tiles, fence + arrival atomic; last block
// does totals + serial walk + emit.
__global__ __launch_bounds__(256) void gated_kernel(
    const float* __restrict__ rois, const float* __restrict__ gts,
    const int* __restrict__ labels,
    int N, int M,
    uint8_t* __restrict__ key, int16_t* __restrict__ bestgt,
    int* __restrict__ grpPk, int* __restrict__ cnt,
    float* __restrict__ outD, float* __restrict__ outH,
    int kgrp, int nblkC, int nWork, int ngroups)
{
#pragma clang fp contract(off)
    __shared__ IouSmem S;
    __shared__ int slot[RPI];
    __shared__ int redP[4], redN[4];
    __shared__ int wTotP[4], wTotN[4];
    __shared__ int s_fast, s_tp, s_tn;

    const int tid = threadIdx.x, w = tid >> 6, l = tid & 63;

    // ---- inline quota check (all blocks; wave 0 computes, LDS broadcast) ----
    if (tid < RPI) slot[tid] = -1;
    if (w == 0) {
        int v = (l < kgrp) ? grpPk[l] : 0;
        int p = v >> 16, n = v & 0xFFFF;
#pragma unroll
        for (int o = 1; o < 64; o <<= 1) {
            p += __shfl_xor(p, o);
            n += __shfl_xor(n, o);
        }
        if (l == 0) s_fast = (p >= MAXPOS && n >= MAXNEG) ? 1 : 0;
    }
    __syncthreads();
    const bool fast = s_fast != 0;

    if (fast) {
        // ================= parallel select over the 4096-key prefix =================
        const int nk = kgrp * 4;             // active threads (16 keys each)
        int kc[16];
        int p = 0, n = 0;
        if (tid < nk) {
            uint4 kv = ((const uint4*)key)[tid];
            unsigned wd[4] = { kv.x, kv.y, kv.z, kv.w };
            const int i0 = tid * 16;
#pragma unroll
            for (int x = 0; x < 4; ++x)
#pragma unroll
                for (int b = 0; b < 4; ++b) {
                    int i = 4 * x + b;
                    int k = (int)((wd[x] >> (8 * b)) & 0xFF);
                    kc[i] = (i0 + i < N) ? k : 2;
                    p += (kc[i] == 0);
                    n += (kc[i] == 1);
                }
        } else {
#pragma unroll
            for (int i = 0; i < 16; ++i) kc[i] = 2;
        }
        // ---- 256-thread exclusive scan of (p, n) ----
        int ip = p, in_ = n;
#pragma unroll
        for (int o = 1; o < 64; o <<= 1) {
            int up = __shfl_up(ip, o), un = __shfl_up(in_, o);
            if (l >= o) { ip += up; in_ += un; }
        }
        if (l == 63) { wTotP[w] = ip; wTotN[w] = in_; }
        __syncthreads();
        int bp = 0, bn = 0;
        for (int x = 0; x < w; ++x) { bp += wTotP[x]; bn += wTotN[x]; }
        int rp = bp + ip - p;                // exclusive global pos rank
        int rn = bn + in_ - n;               // exclusive global neg rank
        // ---- direct slot writes (take-first-k) ----
        const int i0 = tid * 16;
#pragma unroll
        for (int i = 0; i < 16; ++i) {
            if (kc[i] == 0)      { if (rp < MAXPOS) slot[rp] = i0 + i; ++rp; }
            else if (kc[i] == 1) { if (rn < MAXNEG) slot[MAXPOS + rn] = i0 + i; ++rn; }
        }
        __syncthreads();
        // ---- emit: each block owns disjoint rows (4 per block, wave-per-row) ----
        const int stride = gridDim.x * 4;
        for (int row = (int)blockIdx.x * 4 + w; row < RPI; row += stride)
            emit_row(row, slot[row], MAXPOS, l, rois, gts, labels, bestgt, outD, outH);
        return;
    }

    // ========================== slow path (never on bench input) =================
    if ((int)blockIdx.x < nWork) {
        stage_gt(S, gts, M);
        for (int t = (int)blockIdx.x; t < nblkC; t += nWork)
            iou_tile(S, rois, N, M, NBLK_A + t, key, bestgt, grpPk);
        __threadfence();                          // release
        __syncthreads();
        if (tid == 0) atomicAdd(cnt, 1);
        return;
    }
    if (tid == 0) { while (atomicAdd(cnt, 0) < nWork) { } }
    __syncthreads();
    __threadfence();                              // acquire

    {   // totals over all groups
        int sumP = 0, sumN = 0;
        for (int g = tid; g < ngroups; g += 256) {
            int v = grpPk[g];
            sumP += v >> 16;
            sumN += v & 0xFFFF;
        }
#pragma unroll
        for (int o = 32; o > 0; o >>= 1) {
            sumP += __shfl_down(sumP, o);
            sumN += __shfl_down(sumN, o);
        }
        if (l == 0) { redP[w] = sumP; redN[w] = sumN; }
        __syncthreads();
        if (tid == 0) {
            int totP = redP[0] + redP[1] + redP[2] + redP[3];
            int totN = redN[0] + redN[1] + redN[2] + redN[3];
            int tp  = totP < MAXPOS ? totP : MAXPOS;
            int rem = RPI - tp;
            s_tp = tp;
            s_tn = totN < rem ? totN : rem;
        }
    }
    __syncthreads();
    const int tp = s_tp, tn = s_tn;

    if (w == 0) {                                  // serial walk (slow path only)
        int cp = 0, cn = 0;
        int kc = (l < N) ? (int)key[l] : 2;
        for (int g = 0; g < ngroups && (cp < tp || cn < tn); ++g) {
            int i2 = (g + 1) * 64 + l;
            int kn = (g + 1 < ngroups && i2 < N) ? (int)key[i2] : 2;
            unsigned long long mp = __ballot(kc == 0);
            unsigned long long mn = __ballot(kc == 1);
            unsigned long long lt = (1ull << l) - 1ull;
            int i = g * 64 + l;
            if (kc == 0) {
                int rr = cp + __popcll(mp & lt);
                if (rr < tp) slot[rr] = i;
            } else if (kc == 1) {
                int rr = cn + __popcll(mn & lt);
                if (rr < tn) slot[tp + rr] = i;
            }
            cp += __popcll(mp); cn += __popcll(mn);
            kc = kn;
        }
    }
    __syncthreads();
    for (int row = w; row < RPI; row += 4)
        emit_row(row, slot[row], tp, l, rois, gts, labels, bestgt, outD, outH);
}

// ---------------- host launcher ----------------
extern "C" void kernel_launch(void* const* d_in, const int* in_sizes, int n_in,
                              void* d_out, int out_size, void* d_ws, size_t ws_size,
                              hipStream_t stream) {
    const float* rois   = (const float*)d_in[1];   // [1,N,4]
    const float* gts    = (const float*)d_in[2];   // [1,M,4]
    const int*   labels = (const int*)  d_in[3];   // [1,M]
    int N = in_sizes[1] / 4;
    int M = in_sizes[2] / 4;

    char* ws = (char*)d_ws;
    int*     cnt    = (int*)    (ws + WS_CNT);
    int*     grpPk  = (int*)    (ws + WS_GRPPK);
    int16_t* bestgt = (int16_t*)(ws + WS_BESTGT);
    uint8_t* key    = (uint8_t*)(ws + WS_KEY);

    int ngroups = (N + 63) / 64;                   // 64-ROI tiles == groups
    int nblkA   = ngroups < NBLK_A ? ngroups : NBLK_A;
    int kgrp    = nblkA;                           // prefix groups
    int nblkC   = ngroups - nblkA;
    if (nblkC < 0) nblkC = 0;
    int nWork   = nblkC < NBF ? nblkC : NBF;

    float* outD = (float*)d_out;          // [1,256,4]
    float* outH = outD + RPI * 4;         // [1,256,91]

    iouA_kernel<<<nblkA, 256, 0, stream>>>(rois, gts, N, M, key, bestgt, grpPk, cnt);
    gated_kernel<<<nWork + 1, 256, 0, stream>>>(rois, gts, labels, N, M,
                                                key, bestgt, grpPk, cnt,
                                                outD, outH, kgrp, nblkC, nWork, ngroups);
}